// Round 16
// baseline (20.459 us; speedup 1.0000x reference)
//
#include <hip/hip_runtime.h>
#include <math.h>

#define DIM     128
#define V_ROWS  20000
#define NPAIRS  65536
#define NFLOAT4 (V_ROWS * DIM / 4)   // 640000

constexpr int K1_BLOCKS  = 128;
constexpr int K1_THREADS = 512;
constexpr int K1_STRIDE  = K1_BLOCKS * K1_THREADS;       // 65536 float4
constexpr int K1_TAIL    = NFLOAT4 - 9 * K1_STRIDE;      // 50176

constexpr int K2_BLOCKS  = 512;      // 512 x 8 waves = 4096 waves x 16 pairs
constexpr int K2_THREADS = 512;

// ws layout: partial[128*128] f (64 KB), emb_h[20000*128] ushort (5 MB),
//            blockpart[512] f

struct ushort4_t { unsigned short x, y, z, w; };

__device__ __forceinline__ unsigned short f2bf(float f) {   // RNE fp32->bf16
    union { float f; unsigned u; } x; x.f = f;
    const unsigned r = x.u + 0x7FFFu + ((x.u >> 16) & 1u);
    return (unsigned short)(r >> 16);
}
__device__ __forceinline__ float bflo(unsigned u) {         // low bf16 -> f32
    union { unsigned u; float f; } x; x.u = u << 16; return x.f;
}
__device__ __forceinline__ float bfhi(unsigned u) {         // high bf16 -> f32
    union { unsigned u; float f; } x; x.u = u & 0xFFFF0000u; return x.f;
}

// ------ K1: column partial sums + bf16 mirror of the embedding -------------
__global__ __launch_bounds__(K1_THREADS) void k1_colsum(
        const float4* __restrict__ emb4,
        float* __restrict__ partial,
        ushort4_t* __restrict__ emb_h4) {
    const int tid = blockIdx.x * K1_THREADS + threadIdx.x;
    float4 a0 = make_float4(0.f, 0.f, 0.f, 0.f);
    float4 a1 = a0;
    #pragma unroll
    for (int k = 0; k < 8; k += 2) {              // 8 loads, 2 indep chains
        const float4 v0 = emb4[tid + (k + 0) * K1_STRIDE];
        const float4 v1 = emb4[tid + (k + 1) * K1_STRIDE];
        a0.x += v0.x; a0.y += v0.y; a0.z += v0.z; a0.w += v0.w;
        a1.x += v1.x; a1.y += v1.y; a1.z += v1.z; a1.w += v1.w;
        emb_h4[tid + (k + 0) * K1_STRIDE] =
            ushort4_t{ f2bf(v0.x), f2bf(v0.y), f2bf(v0.z), f2bf(v0.w) };
        emb_h4[tid + (k + 1) * K1_STRIDE] =
            ushort4_t{ f2bf(v1.x), f2bf(v1.y), f2bf(v1.z), f2bf(v1.w) };
    }
    {   // round 8 + predicated tail round 9
        const float4 v0 = emb4[tid + 8 * K1_STRIDE];
        a0.x += v0.x; a0.y += v0.y; a0.z += v0.z; a0.w += v0.w;
        emb_h4[tid + 8 * K1_STRIDE] =
            ushort4_t{ f2bf(v0.x), f2bf(v0.y), f2bf(v0.z), f2bf(v0.w) };
        if (tid < K1_TAIL) {
            const float4 v1 = emb4[tid + 9 * K1_STRIDE];
            a1.x += v1.x; a1.y += v1.y; a1.z += v1.z; a1.w += v1.w;
            emb_h4[tid + 9 * K1_STRIDE] =
                ushort4_t{ f2bf(v1.x), f2bf(v1.y), f2bf(v1.z), f2bf(v1.w) };
        }
    }
    float4 a = make_float4(a0.x + a1.x, a0.y + a1.y,
                           a0.z + a1.z, a0.w + a1.w);
    // stride*4 % 128 == 0 -> thread's 4 cols fixed: (tid*4)&127.
    // lane l and l^32 share columns -> fold wave to 32 lanes.
    a.x += __shfl_xor(a.x, 32);
    a.y += __shfl_xor(a.y, 32);
    a.z += __shfl_xor(a.z, 32);
    a.w += __shfl_xor(a.w, 32);

    __shared__ float sm[8][DIM];          // 8 waves per block
    const int wid  = threadIdx.x >> 6;
    const int lane = threadIdx.x & 63;
    const int col  = (threadIdx.x * 4) & 127;
    if (lane < 32) {
        sm[wid][col + 0] = a.x;
        sm[wid][col + 1] = a.y;
        sm[wid][col + 2] = a.z;
        sm[wid][col + 3] = a.w;
    }
    __syncthreads();
    if (threadIdx.x < DIM) {
        float tot = 0.f;
        #pragma unroll
        for (int w = 0; w < 8; ++w) tot += sm[w][threadIdx.x];
        partial[blockIdx.x * DIM + threadIdx.x] = tot;
    }
}

// ------- K2: fold -> S_lds (fp32); pairs gather bf16 rows (256 B/row) ------
__global__ __launch_bounds__(K2_THREADS) void k2_pairs(
        const unsigned short* __restrict__ emb_h,  // [20000][128] bf16
        const int* __restrict__ iv,
        const int* __restrict__ jv,
        const float4* __restrict__ partial4,       // [128][32] float4
        float* __restrict__ blockpart) {
    const int lane = threadIdx.x & 63;
    const int wid  = threadIdx.x >> 6;     // 0..7

    __shared__ float4 sm4[16][32];
    __shared__ float  S_lds[DIM];
    __shared__ float  ls[8];

    // ---- fold 128 partial rows -> S_lds (8 f4 loads/thread, 2 chains) -----
    {
        const int f4c = threadIdx.x & 31;     // float4 column 0..31
        const int g   = threadIdx.x >> 5;     // row group 0..15, 8 rows each
        float4 c0 = make_float4(0.f, 0.f, 0.f, 0.f);
        float4 c1 = c0;
        #pragma unroll
        for (int k = 0; k < 8; k += 2) {
            const float4 v0 = partial4[(g + 16 * (k + 0)) * 32 + f4c];
            const float4 v1 = partial4[(g + 16 * (k + 1)) * 32 + f4c];
            c0.x += v0.x; c0.y += v0.y; c0.z += v0.z; c0.w += v0.w;
            c1.x += v1.x; c1.y += v1.y; c1.z += v1.z; c1.w += v1.w;
        }
        float4 s;
        s.x = c0.x + c1.x; s.y = c0.y + c1.y;
        s.z = c0.z + c1.z; s.w = c0.w + c1.w;
        sm4[g][f4c] = s;
        __syncthreads();
        if (threadIdx.x < DIM) {
            const float* smf = reinterpret_cast<const float*>(sm4); // [16][128]
            float tot = 0.f;
            #pragma unroll
            for (int g2 = 0; g2 < 16; ++g2) tot += smf[g2 * DIM + threadIdx.x];
            S_lds[threadIdx.x] = tot;
        }
        __syncthreads();
    }

    // ---------------- pairs: 16 lanes/pair, 16 pairs/wave, ONE round -------
    const int c    = lane & 15;            // 8 bf16 cols per lane
    const int grp  = lane >> 4;            // 4 pairs in flight per batch
    const int gw   = blockIdx.x * 8 + wid; // 0..4095
    const int base = gw * 16;              // wave's 16 consecutive pairs

    const float4* S4 = reinterpret_cast<const float4*>(S_lds);
    const float4 s0 = S4[c * 2], s1 = S4[c * 2 + 1];

    // coalesced index load: lanes 0..15 -> iv, lanes 16..31 -> jv
    int idxval = 0;
    if (lane < 16)      idxval = iv[base + lane];
    else if (lane < 32) idxval = jv[base + lane - 16];

    // issue ALL 16 row-pair gathers (one uint4 = 8 bf16 per lane per row)
    uint4 A[4], B[4];
    #pragma unroll
    for (int it = 0; it < 4; ++it) {
        const int q = it * 4 + grp;
        const int i = __shfl(idxval, q);
        const int j = __shfl(idxval, 16 + q);
        A[it] = reinterpret_cast<const uint4*>(emb_h + (size_t)i * DIM)[c];
        B[it] = reinterpret_cast<const uint4*>(emb_h + (size_t)j * DIM)[c];
    }

    float acc = 0.f;
    #pragma unroll
    for (int it = 0; it < 4; ++it) {
        // fused dot: m = e_i . (e_j - S)  ==  d - n  (bf16 rows, fp32 S)
        float m = bflo(A[it].x) * (bflo(B[it].x) - s0.x)
                + bfhi(A[it].x) * (bfhi(B[it].x) - s0.y)
                + bflo(A[it].y) * (bflo(B[it].y) - s0.z)
                + bfhi(A[it].y) * (bfhi(B[it].y) - s0.w)
                + bflo(A[it].z) * (bflo(B[it].z) - s1.x)
                + bfhi(A[it].z) * (bfhi(B[it].z) - s1.y)
                + bflo(A[it].w) * (bflo(B[it].w) - s1.z)
                + bfhi(A[it].w) * (bfhi(B[it].w) - s1.w);
        #pragma unroll
        for (int off = 8; off > 0; off >>= 1) m += __shfl_xor(m, off);
        const float cost = -__logf(__expf(m) + 1e-8f);
        if (c == 0) acc += cost;           // grp leaders only
    }
    // fold grp leaders (lanes 0,16,32,48) -> lane 0
    acc += __shfl_xor(acc, 16);
    acc += __shfl_xor(acc, 32);

    if (lane == 0) ls[wid] = acc;
    __syncthreads();
    if (threadIdx.x == 0) {
        float s = 0.f;
        #pragma unroll
        for (int w = 0; w < 8; ++w) s += ls[w];
        blockpart[blockIdx.x] = s;
    }
}

// ---------------- K3: final reduce (1 block, one parallel load round) ------
__global__ __launch_bounds__(256) void k3_final(
        const float* __restrict__ blockpart,
        float* __restrict__ out) {
    const int t = threadIdx.x;             // 0..255
    float s = blockpart[t] + blockpart[t + 256];
    #pragma unroll
    for (int off = 32; off > 0; off >>= 1) s += __shfl_xor(s, off);
    __shared__ float ls[4];
    if ((t & 63) == 0) ls[t >> 6] = s;
    __syncthreads();
    if (t == 0)
        out[0] = (ls[0] + ls[1] + ls[2] + ls[3]) / (float)NPAIRS;
}

extern "C" void kernel_launch(void* const* d_in, const int* in_sizes, int n_in,
                              void* d_out, int out_size, void* d_ws, size_t ws_size,
                              hipStream_t stream) {
    const float4* emb4 = (const float4*)d_in[0];
    const int*    iv   = (const int*)d_in[1];
    const int*    jv   = (const int*)d_in[2];
    float* out = (float*)d_out;

    float*          partial   = (float*)d_ws;                        // 64 KB
    unsigned short* emb_h     = (unsigned short*)((char*)d_ws + K1_BLOCKS * DIM * 4);
    float*          blockpart = (float*)((char*)d_ws + K1_BLOCKS * DIM * 4
                                         + (size_t)V_ROWS * DIM * 2);

    hipLaunchKernelGGL(k1_colsum, dim3(K1_BLOCKS), dim3(K1_THREADS), 0, stream,
                       emb4, partial, (ushort4_t*)emb_h);
    hipLaunchKernelGGL(k2_pairs, dim3(K2_BLOCKS), dim3(K2_THREADS), 0, stream,
                       emb_h, iv, jv, (const float4*)partial, blockpart);
    hipLaunchKernelGGL(k3_final, dim3(1), dim3(256), 0, stream,
                       blockpart, out);
}